// Round 3
// baseline (737.096 us; speedup 1.0000x reference)
//
#include <hip/hip_runtime.h>

// ---------------------------------------------------------------------------
// Fused 2-layer LSTM, N=8192, T=28, I=28, H=128, + final [128->10] linear.
// R3: WAVE-SPECIALIZED PIPELINE.
//   waves 0-3 ("L0") compute layer0 step s; waves 4-7 ("L1") compute layer1
//   step s-1 concurrently (layer0(t+1) is independent of layer1(t)).
//   One barrier per stage, 29 stages (vs 2 barriers x 28 steps before).
//   Each SIMD hosts one L0 + one L1 wave -> MFMA/VALU/LDS pipes of the two
//   phases overlap instead of serializing (R2 ran 80% idle, MfmaUtil 18%).
// Residency:
//   L0 wave: whh0 (128 reg) + wih0 (32 reg) persistent in VGPR/AGPR.
//   L1 wave: whh1 (128 reg) + wih1_kc0 (32 reg) persistent; wih1 kc1-3 in LDS.
//   h0, h1: double-buffered A-frag tiles in LDS. x: global->reg, prefetched
//   one stage ahead (no LDS, no barrier coupling).
// LDS = 96K (wih1 kc1-3) + 16K (h0 x2) + 16K (h1 x2) = 128 KB.
// ---------------------------------------------------------------------------

typedef short  short8   __attribute__((ext_vector_type(8)));
typedef float  float4_t __attribute__((ext_vector_type(4)));

#define WIH1_OFF 0        //  98304 B : wih1 kc1..3 [(kc-1)*32+nt][lane][8]
#define H0_OFF   98304    //  16384 B : h0, 2 buffers x 8192
#define H1_OFF   114688   //  16384 B : h1, 2 buffers x 8192
#define SMEM_SZ  131072

__device__ __forceinline__ unsigned short bf16r(float v) {
  union { float f; unsigned u; } x; x.f = v;
  unsigned r = x.u + 0x7fffu + ((x.u >> 16) & 1u);   // round-to-nearest-even
  return (unsigned short)(r >> 16);
}
__device__ __forceinline__ float bf2f(unsigned short b) {
  union { unsigned u; float f; } x; x.u = ((unsigned)b) << 16;
  return x.f;
}
__device__ __forceinline__ float sigf(float x)  { return 1.0f / (1.0f + __expf(-x)); }
__device__ __forceinline__ float tanhfast(float x) { return 1.0f - 2.0f / (__expf(2.0f * x) + 1.0f); }

// ---------------------------------------------------------------------------
// Prologue: pack weights (fp32 -> bf16) into MFMA B-frag tiled layout in ws.
// ws (unsigned short units):
//   [0      ,16384) : w_ih0  [1 kc][32 tiles][64 lanes][8]  (k padded to 32)
//   [16384  ,81920) : w_hh0  [4 kc][32 tiles][64][8]
//   [81920 ,147456) : w_ih1  [4 kc][32][64][8]
//   [147456,212992) : w_hh1  [4 kc][32][64][8]
// element (tile,lane,j): row = tile*16 + (lane&15), k = kc*32 + (lane>>4)*8 + j
// ---------------------------------------------------------------------------
__global__ void pack_weights(const float* __restrict__ wih0, const float* __restrict__ whh0,
                             const float* __restrict__ wih1, const float* __restrict__ whh1,
                             unsigned short* __restrict__ dst)
{
  int e = blockIdx.x * 256 + threadIdx.x;
  const float* src; int K; int i;
  if      (e < 16384)  { src = wih0; K = 28;  i = e;          }
  else if (e < 81920)  { src = whh0; K = 128; i = e - 16384;  }
  else if (e < 147456) { src = wih1; K = 128; i = e - 81920;  }
  else if (e < 212992) { src = whh1; K = 128; i = e - 147456; }
  else return;
  int j = i & 7, lane = (i >> 3) & 63, tile = (i >> 9) & 31, kc = i >> 14;
  int row = tile * 16 + (lane & 15);
  int k = kc * 32 + ((lane >> 4) << 3) + j;
  float v = (k < K) ? src[row * K + k] : 0.0f;
  dst[e] = bf16r(v);
}

// ---------------------------------------------------------------------------
// Main fused kernel. grid 256 x 512 (1 block/CU).
// ---------------------------------------------------------------------------
__global__ __launch_bounds__(512, 2)
__attribute__((amdgpu_waves_per_eu(2, 2)))
void lstm_fused(const float* __restrict__ xg,
                const unsigned short* __restrict__ wpack,
                const float* __restrict__ bih0, const float* __restrict__ bhh0,
                const float* __restrict__ bih1, const float* __restrict__ bhh1,
                const float* __restrict__ wout, const float* __restrict__ bout,
                float* __restrict__ out)
{
  __shared__ __align__(16) char smem[SMEM_SZ];

  const int tid  = threadIdx.x;
  const int lane = tid & 63;
  const int wave = tid >> 6;          // 0..7
  const bool isL0 = wave < 4;
  const int w    = wave & 3;          // slice index within group: hslices {2w,2w+1}
  const int q    = lane >> 4;         // quad
  const int mcol = lane & 15;
  const int n0   = blockIdx.x * 32;   // batch tile base

  const short8* wp = (const short8*)wpack;

  // ---- persistent weight fragments in registers (160 regs/wave) ----------
  // L0: wb = whh0 slice, wi = wih0 slice (kc0, k=x-dims padded to 32).
  // L1: wb = whh1 slice, wi = wih1 kc0 slice.
  short8 wb[4][8], wi[8];             // [kc][g*2+hs] / [g*2+hs]
  {
    const short8* whh_b = wp + (isL0 ? 2048 : 18432);
    const short8* wih_b = wp + (isL0 ? 0 : 10240);
#pragma unroll
    for (int kc = 0; kc < 4; ++kc)
#pragma unroll
      for (int g = 0; g < 4; ++g)
#pragma unroll
        for (int hs = 0; hs < 2; ++hs)
          wb[kc][g * 2 + hs] = whh_b[(kc * 32 + g * 8 + 2 * w + hs) * 64 + lane];
#pragma unroll
    for (int g = 0; g < 4; ++g)
#pragma unroll
      for (int hs = 0; hs < 2; ++hs)
        wi[g * 2 + hs] = wih_b[(g * 8 + 2 * w + hs) * 64 + lane];
  }

  // ---- wih1 kc1..3 -> LDS (98304 B; source region is contiguous) ---------
  {
    short8* wl = (short8*)smem;
#pragma unroll
    for (int r = 0; r < 12; ++r)
      wl[r * 512 + tid] = wp[10240 + 2048 + r * 512 + tid];
  }

  // ---- biases: per lane, [g*2+hs] for dim = (2w+hs)*16 + mcol ------------
  float bias[8];
  {
    const float* bi = isL0 ? bih0 : bih1;
    const float* bh = isL0 ? bhh0 : bhh1;
#pragma unroll
    for (int g = 0; g < 4; ++g)
#pragma unroll
      for (int hs = 0; hs < 2; ++hs) {
        int d = g * 128 + (2 * w + hs) * 16 + mcol;
        bias[g * 2 + hs] = bi[d] + bh[d];
      }
  }

  // ---- zero the "prev" h buffers (parity 1) ------------------------------
  {
    int* z0 = (int*)(smem + H0_OFF + 8192);
    int* z1 = (int*)(smem + H1_OFF + 8192);
#pragma unroll
    for (int r = 0; r < 4; ++r) { z0[r * 512 + tid] = 0; z1[r * 512 + tid] = 0; }
  }

  // ---- x loader: global fp32 -> raw float4 regs (L0 waves only) ----------
  // A-frag (m=sample, k=xdim): sample = mt*16+mcol, k = q*8+j (k>=28 -> 0).
  float4_t xlo[2], xhi[2];
  auto load_x = [&](int t) {
#pragma unroll
    for (int mt = 0; mt < 2; ++mt) {
      const float* p = xg + (size_t)(n0 + mt * 16 + mcol) * 784 + t * 28 + q * 8;
      xlo[mt] = *(const float4_t*)p;
      xhi[mt] = (q < 3) ? *(const float4_t*)(p + 4) : (float4_t){0.f, 0.f, 0.f, 0.f};
    }
  };
  auto cvt_frag = [&](float4_t lo, float4_t hi) -> short8 {
    short8 f;
    f[0] = (short)bf16r(lo[0]); f[1] = (short)bf16r(lo[1]);
    f[2] = (short)bf16r(lo[2]); f[3] = (short)bf16r(lo[3]);
    f[4] = (short)bf16r(hi[0]); f[5] = (short)bf16r(hi[1]);
    f[6] = (short)bf16r(hi[2]); f[7] = (short)bf16r(hi[3]);
    return f;
  };
  if (isL0) load_x(0);

  // per-lane constant part of h-write address: element (sample, d) with
  // d = (2w+hs)*16+mcol at A-frag position; kc-chunk of d is exactly w.
  const int hwbase = w * 1024 + ((mcol >> 3) << 8) + (q << 6) + ((mcol & 7) << 1);

  float cst[16];                      // c-state [mt][hs][r], fp32
#pragma unroll
  for (int i = 0; i < 16; ++i) cst[i] = 0.f;

  __syncthreads();   // LDS weights staged, h zeroed

  // =========================== pipeline ===================================
  // stage s: L0 computes h0(s) (s<28); L1 computes h1(s-1) (s>=1).
#pragma unroll 1
  for (int s = 0; s < 29; ++s) {
    if (isL0) {
      if (s < 28) {
        const short8* h0prev = (const short8*)(smem + H0_OFF + ((s + 1) & 1) * 8192);
        char*         h0cur  = smem + H0_OFF + (s & 1) * 8192;
        short8 xf[2];
        xf[0] = cvt_frag(xlo[0], xhi[0]);
        xf[1] = cvt_frag(xlo[1], xhi[1]);
        if (s + 1 < 28) load_x(s + 1);           // prefetch next stage's x
#pragma unroll
        for (int mt = 0; mt < 2; ++mt) {
          short8 ha[4];
#pragma unroll
          for (int kc = 0; kc < 4; ++kc)
            ha[kc] = h0prev[(mt * 4 + kc) * 64 + lane];
#pragma unroll
          for (int hs = 0; hs < 2; ++hs) {
            float4_t ac[4];
#pragma unroll
            for (int g = 0; g < 4; ++g) {
              float b = bias[g * 2 + hs];
              ac[g] = (float4_t){b, b, b, b};
            }
#pragma unroll
            for (int kc = 0; kc < 4; ++kc)
#pragma unroll
              for (int g = 0; g < 4; ++g)
                ac[g] = __builtin_amdgcn_mfma_f32_16x16x32_bf16(ha[kc], wb[kc][g * 2 + hs], ac[g], 0, 0, 0);
#pragma unroll
            for (int g = 0; g < 4; ++g)
              ac[g] = __builtin_amdgcn_mfma_f32_16x16x32_bf16(xf[mt], wi[g * 2 + hs], ac[g], 0, 0, 0);
#pragma unroll
            for (int r = 0; r < 4; ++r) {
              int ci = (mt * 2 + hs) * 4 + r;
              float ig = sigf(ac[0][r]), fg = sigf(ac[1][r]);
              float gg = tanhfast(ac[2][r]), og = sigf(ac[3][r]);
              float c  = fg * cst[ci] + ig * gg;
              cst[ci]  = c;
              *(unsigned short*)(h0cur + mt * 4096 + hs * 512 + r * 16 + hwbase) =
                  bf16r(og * tanhfast(c));
            }
          }
        }
      }
    } else {
      if (s >= 1) {
        const short8* h0p = (const short8*)(smem + H0_OFF + ((s + 1) & 1) * 8192); // h0(s-1)
        const short8* h1p = (const short8*)(smem + H1_OFF + (s & 1) * 8192);       // h1(s-2)
        char*         h1c = smem + H1_OFF + ((s + 1) & 1) * 8192;                  // h1(s-1)
        const short8* WL  = (const short8*)smem;
#pragma unroll
        for (int mt = 0; mt < 2; ++mt) {
          short8 ha[4], hb[4];
#pragma unroll
          for (int kc = 0; kc < 4; ++kc) {
            ha[kc] = h0p[(mt * 4 + kc) * 64 + lane];
            hb[kc] = h1p[(mt * 4 + kc) * 64 + lane];
          }
#pragma unroll
          for (int hs = 0; hs < 2; ++hs) {
            float4_t ac[4];
#pragma unroll
            for (int g = 0; g < 4; ++g) {
              float b = bias[g * 2 + hs];
              ac[g] = (float4_t){b, b, b, b};
            }
#pragma unroll
            for (int g = 0; g < 4; ++g)
              ac[g] = __builtin_amdgcn_mfma_f32_16x16x32_bf16(ha[0], wi[g * 2 + hs], ac[g], 0, 0, 0);
#pragma unroll
            for (int kc = 1; kc < 4; ++kc)
#pragma unroll
              for (int g = 0; g < 4; ++g)
                ac[g] = __builtin_amdgcn_mfma_f32_16x16x32_bf16(
                    ha[kc], WL[((kc - 1) * 32 + g * 8 + 2 * w + hs) * 64 + lane], ac[g], 0, 0, 0);
#pragma unroll
            for (int kc = 0; kc < 4; ++kc)
#pragma unroll
              for (int g = 0; g < 4; ++g)
                ac[g] = __builtin_amdgcn_mfma_f32_16x16x32_bf16(hb[kc], wb[kc][g * 2 + hs], ac[g], 0, 0, 0);
#pragma unroll
            for (int r = 0; r < 4; ++r) {
              int ci = (mt * 2 + hs) * 4 + r;
              float ig = sigf(ac[0][r]), fg = sigf(ac[1][r]);
              float gg = tanhfast(ac[2][r]), og = sigf(ac[3][r]);
              float c  = fg * cst[ci] + ig * gg;
              cst[ci]  = c;
              *(unsigned short*)(h1c + mt * 4096 + hs * 512 + r * 16 + hwbase) =
                  bf16r(og * tanhfast(c));
            }
          }
        }
      }
    }
    __syncthreads();
  }

  // ================= epilogue: out[s][o] = h1(27) . wout[o] + bout[o] =====
  // h1(27) is in buffer parity 1.
  const short8* H1f = (const short8*)(smem + H1_OFF + 8192);
  if (tid < 320) {
    int s = tid / 10, o = tid - (tid / 10) * 10;
    float sum = bout[o];
#pragma unroll
    for (int kc = 0; kc < 4; ++kc)
#pragma unroll
      for (int sb = 0; sb < 4; ++sb) {
        short8 hv = H1f[((s >> 4) * 4 + kc) * 64 + sb * 16 + (s & 15)];
        int dbase = kc * 32 + sb * 8;
        float4_t w0 = *(const float4_t*)(wout + o * 128 + dbase);
        float4_t w1 = *(const float4_t*)(wout + o * 128 + dbase + 4);
#pragma unroll
        for (int j = 0; j < 4; ++j) {
          sum += bf2f((unsigned short)hv[j])     * w0[j];
          sum += bf2f((unsigned short)hv[j + 4]) * w1[j];
        }
      }
    out[(size_t)(n0 + s) * 10 + o] = sum;
  }
}

extern "C" void kernel_launch(void* const* d_in, const int* in_sizes, int n_in,
                              void* d_out, int out_size, void* d_ws, size_t ws_size,
                              hipStream_t stream) {
  const float* x    = (const float*)d_in[0];
  const float* wih0 = (const float*)d_in[1];
  const float* whh0 = (const float*)d_in[2];
  const float* bih0 = (const float*)d_in[3];
  const float* bhh0 = (const float*)d_in[4];
  const float* wih1 = (const float*)d_in[5];
  const float* whh1 = (const float*)d_in[6];
  const float* bih1 = (const float*)d_in[7];
  const float* bhh1 = (const float*)d_in[8];
  const float* wout = (const float*)d_in[9];
  const float* bout = (const float*)d_in[10];

  unsigned short* wp = (unsigned short*)d_ws;   // 425984 B used

  pack_weights<<<832, 256, 0, stream>>>(wih0, whh0, wih1, whh1, wp);
  lstm_fused<<<256, 512, 0, stream>>>(x, wp, bih0, bhh0, bih1, bhh1, wout, bout,
                                      (float*)d_out);
}

// Round 4
// 359.314 us; speedup vs baseline: 2.0514x; 2.0514x over previous
//
#include <hip/hip_runtime.h>

// ---------------------------------------------------------------------------
// Fused 2-layer LSTM, N=8192, T=28, I=28, H=128, + final [128->10] linear.
// R4: 256-thread blocks (4 waves), 1 wave/SIMD, 512-reg unified budget/wave.
//   R3 spilled (FETCH 1.5 GB) because 2 waves/SIMD caps at 256 regs; R4 gives
//   each wave the full 512-reg file: whh0+whh1+wih0 slices resident (288 regs),
//   wih1 in LDS (128 KB). Block processes 2 halves of 16 samples each,
//   reusing resident weights. Lockstep, 2 barriers/step over only 4 waves;
//   each SIMD has exactly 1 wave -> no intra-SIMD phase serialization.
//   bias0 folded into x-MFMA padding slot k=28 (x=1.0, wih0[.,28]=bih0+bhh0).
// LDS = 128K (wih1) + 8K (h0 x2) + 8K (h1 x2) = 144 KB.
// ---------------------------------------------------------------------------

typedef short  short8   __attribute__((ext_vector_type(8)));
typedef float  float4_t __attribute__((ext_vector_type(4)));

#define WIH1_OFF 0        // 131072 B : wih1 [4kc][32nt][64 lane][8] bf16 frags
#define H0_OFF   131072   //   8192 B : h0, 2 buffers x 4096
#define H1_OFF   139264   //   8192 B : h1, 2 buffers x 4096
#define SMEM_SZ  147456

__device__ __forceinline__ unsigned short bf16r(float v) {
  union { float f; unsigned u; } x; x.f = v;
  unsigned r = x.u + 0x7fffu + ((x.u >> 16) & 1u);   // round-to-nearest-even
  return (unsigned short)(r >> 16);
}
__device__ __forceinline__ float bf2f(unsigned short b) {
  union { unsigned u; float f; } x; x.u = ((unsigned)b) << 16;
  return x.f;
}
__device__ __forceinline__ float sigf(float x)  { return 1.0f / (1.0f + __expf(-x)); }
__device__ __forceinline__ float tanhfast(float x) { return 1.0f - 2.0f / (__expf(2.0f * x) + 1.0f); }

// ---------------------------------------------------------------------------
// Prologue: pack weights (fp32 -> bf16) into MFMA B-frag tiled layout in ws.
// ws (unsigned short units):
//   [0      ,16384) : w_ih0  [1 kc][32 tiles][64 lanes][8] (k padded to 32;
//                     k==28 slot holds bih0+bhh0 -> bias folded into x-MFMA)
//   [16384  ,81920) : w_hh0  [4 kc][32 tiles][64][8]
//   [81920 ,147456) : w_ih1  [4 kc][32][64][8]
//   [147456,212992) : w_hh1  [4 kc][32][64][8]
// element (tile,lane,j): row = tile*16 + (lane&15), k = kc*32 + (lane>>4)*8 + j
// ---------------------------------------------------------------------------
__global__ void pack_weights(const float* __restrict__ wih0, const float* __restrict__ whh0,
                             const float* __restrict__ wih1, const float* __restrict__ whh1,
                             const float* __restrict__ bih0, const float* __restrict__ bhh0,
                             unsigned short* __restrict__ dst)
{
  int e = blockIdx.x * 256 + threadIdx.x;
  const float* src; int K; int i; bool isW0 = false;
  if      (e < 16384)  { src = wih0; K = 28;  i = e;          isW0 = true; }
  else if (e < 81920)  { src = whh0; K = 128; i = e - 16384;  }
  else if (e < 147456) { src = wih1; K = 128; i = e - 81920;  }
  else if (e < 212992) { src = whh1; K = 128; i = e - 147456; }
  else return;
  int j = i & 7, lane = (i >> 3) & 63, tile = (i >> 9) & 31, kc = i >> 14;
  int row = tile * 16 + (lane & 15);
  int k = kc * 32 + ((lane >> 4) << 3) + j;
  float v;
  if (k < K)                 v = src[row * K + k];
  else if (isW0 && k == 28)  v = bih0[row] + bhh0[row];   // folded bias0
  else                       v = 0.0f;
  dst[e] = bf16r(v);
}

// ---------------------------------------------------------------------------
// Main fused kernel. grid 256 x 256 threads (4 waves), 1 wave/SIMD.
// Wave w owns gate-rows nt = g*8 + 2w + hs (g=0..3, hs=0..1)
//   -> h-dims [32w, 32w+32) for every gate (c-update stays thread-local).
// ---------------------------------------------------------------------------
__global__ __launch_bounds__(256, 1)
__attribute__((amdgpu_waves_per_eu(1, 1)))
void lstm_fused(const float* __restrict__ xg,
                const unsigned short* __restrict__ wpack,
                const float* __restrict__ bih1, const float* __restrict__ bhh1,
                const float* __restrict__ wout, const float* __restrict__ bout,
                float* __restrict__ out)
{
  __shared__ __align__(16) char smem[SMEM_SZ];

  const int tid  = threadIdx.x;
  const int lane = tid & 63;
  const int w    = tid >> 6;          // wave 0..3
  const int q    = lane >> 4;         // quad -> acc rows (samples) q*4..q*4+3
  const int mcol = lane & 15;         // acc col = gate-dim within tile

  const short8* wp = (const short8*)wpack;

  // ---- persistent weight slices in registers (288 regs) ------------------
  short8 whh0[4][8], whh1[4][8], wih0[8];      // [kc][g*2+hs] / [g*2+hs]
#pragma unroll
  for (int kc = 0; kc < 4; ++kc)
#pragma unroll
    for (int g = 0; g < 4; ++g)
#pragma unroll
      for (int hs = 0; hs < 2; ++hs) {
        whh0[kc][g * 2 + hs] = wp[ 2048 + (kc * 32 + g * 8 + 2 * w + hs) * 64 + lane];
        whh1[kc][g * 2 + hs] = wp[18432 + (kc * 32 + g * 8 + 2 * w + hs) * 64 + lane];
      }
#pragma unroll
  for (int g = 0; g < 4; ++g)
#pragma unroll
    for (int hs = 0; hs < 2; ++hs)
      wih0[g * 2 + hs] = wp[(g * 8 + 2 * w + hs) * 64 + lane];

  // ---- wih1 -> LDS (131072 B) --------------------------------------------
  {
    short8* wl = (short8*)smem;
#pragma unroll
    for (int r = 0; r < 32; ++r)
      wl[r * 256 + tid] = wp[10240 + r * 256 + tid];
  }

  // ---- bias1 (8 regs) -----------------------------------------------------
  float bias1[8];
#pragma unroll
  for (int g = 0; g < 4; ++g)
#pragma unroll
    for (int hs = 0; hs < 2; ++hs) {
      int d = g * 128 + (2 * w + hs) * 16 + mcol;
      bias1[g * 2 + hs] = bih1[d] + bhh1[d];
    }

  // per-lane constant part of the h-write address: element (s, d),
  // d = (2w+hs)*16+mcol -> kc-chunk w, lane' = (2hs+(mcol>>3))*16 + s, j=mcol&7
  const int hwc = w * 1024 + ((mcol >> 3) << 8) + (q << 6) + ((mcol & 7) << 1);

  const short8* W1 = (const short8*)smem;    // wih1 frags [kc*32+nt][lane]

#pragma unroll 1
  for (int half = 0; half < 2; ++half) {
    const int n0 = blockIdx.x * 32 + half * 16;

    // zero parity-1 h buffers (step 0 reads them)
    {
      int* z0 = (int*)(smem + H0_OFF + 4096);
      int* z1 = (int*)(smem + H1_OFF + 4096);
#pragma unroll
      for (int r = 0; r < 4; ++r) { z0[r * 256 + tid] = 0; z1[r * 256 + tid] = 0; }
    }

    float cst0[8], cst1[8];
#pragma unroll
    for (int i = 0; i < 8; ++i) { cst0[i] = 0.f; cst1[i] = 0.f; }

    // x A-frag loader: sample m = mcol, k = q*8+j; k==28 -> 1.0 (bias slot)
    float4_t xlo, xhi;
    auto load_x = [&](int t) {
      const float* p = xg + (size_t)(n0 + mcol) * 784 + t * 28 + q * 8;
      xlo = *(const float4_t*)p;
      xhi = (q < 3) ? *(const float4_t*)(p + 4) : (float4_t){1.f, 0.f, 0.f, 0.f};
    };
    load_x(0);
    __syncthreads();   // wih1 staged (half 0) / h zeroed; prev epilogue done

#pragma unroll 1
    for (int t = 0; t < 28; ++t) {
      const char* h0p = smem + H0_OFF + ((t + 1) & 1) * 4096;
      char*       h0c = smem + H0_OFF + (t & 1) * 4096;
      float4_t ac[8];

      // ============ LAYER 0: gates = x_t@[wih0|b0] + h0@whh0 ==============
      short8 xf;
#pragma unroll
      for (int j = 0; j < 4; ++j) {
        xf[j]     = (short)bf16r(xlo[j]);
        xf[j + 4] = (short)bf16r(xhi[j]);
      }
      if (t < 27) load_x(t + 1);               // prefetch next step's x
      short8 ha[4];
#pragma unroll
      for (int kc = 0; kc < 4; ++kc)
        ha[kc] = ((const short8*)h0p)[kc * 64 + lane];
#pragma unroll
      for (int i = 0; i < 8; ++i)
        ac[i] = __builtin_amdgcn_mfma_f32_16x16x32_bf16(xf, wih0[i],
                    (float4_t){0.f, 0.f, 0.f, 0.f}, 0, 0, 0);
#pragma unroll
      for (int kc = 0; kc < 4; ++kc)
#pragma unroll
        for (int i = 0; i < 8; ++i)
          ac[i] = __builtin_amdgcn_mfma_f32_16x16x32_bf16(ha[kc], whh0[kc][i], ac[i], 0, 0, 0);
      // activations (i,f,g,o) + h0 write
#pragma unroll
      for (int hs = 0; hs < 2; ++hs)
#pragma unroll
        for (int r = 0; r < 4; ++r) {
          float ig = sigf(ac[0 + hs][r]), fg = sigf(ac[2 + hs][r]);
          float gg = tanhfast(ac[4 + hs][r]), og = sigf(ac[6 + hs][r]);
          float c  = fg * cst0[hs * 4 + r] + ig * gg;
          cst0[hs * 4 + r] = c;
          *(unsigned short*)(h0c + hs * 512 + r * 16 + hwc) = bf16r(og * tanhfast(c));
        }
      __syncthreads();   // h0_t visible

      // ============ LAYER 1: gates = b1 + h0_t@wih1 + h1@whh1 =============
      const char* h1p = smem + H1_OFF + ((t + 1) & 1) * 4096;
      char*       h1c = smem + H1_OFF + (t & 1) * 4096;
      short8 hb[4], hc[4];
#pragma unroll
      for (int kc = 0; kc < 4; ++kc) {
        hb[kc] = ((const short8*)h0c)[kc * 64 + lane];
        hc[kc] = ((const short8*)h1p)[kc * 64 + lane];
      }
#pragma unroll
      for (int i = 0; i < 8; ++i) {
        float b = bias1[i];
        ac[i] = (float4_t){b, b, b, b};
      }
#pragma unroll
      for (int kc = 0; kc < 4; ++kc)
#pragma unroll
        for (int i = 0; i < 8; ++i)
          ac[i] = __builtin_amdgcn_mfma_f32_16x16x32_bf16(
                      hb[kc], W1[(kc * 32 + (i >> 1) * 8 + 2 * w + (i & 1)) * 64 + lane],
                      ac[i], 0, 0, 0);
#pragma unroll
      for (int kc = 0; kc < 4; ++kc)
#pragma unroll
        for (int i = 0; i < 8; ++i)
          ac[i] = __builtin_amdgcn_mfma_f32_16x16x32_bf16(hc[kc], whh1[kc][i], ac[i], 0, 0, 0);
      // activations + h1 write
#pragma unroll
      for (int hs = 0; hs < 2; ++hs)
#pragma unroll
        for (int r = 0; r < 4; ++r) {
          float ig = sigf(ac[0 + hs][r]), fg = sigf(ac[2 + hs][r]);
          float gg = tanhfast(ac[4 + hs][r]), og = sigf(ac[6 + hs][r]);
          float c  = fg * cst1[hs * 4 + r] + ig * gg;
          cst1[hs * 4 + r] = c;
          *(unsigned short*)(h1c + hs * 512 + r * 16 + hwc) = bf16r(og * tanhfast(c));
        }
      __syncthreads();   // h1_t visible; h0p safe to overwrite next step
    }

    // ============ epilogue: out[s][o] = h1(27) . wout[o] + bout[o] =========
    // t=27 wrote parity 1.
    const short8* H1f = (const short8*)(smem + H1_OFF + 4096);
    if (tid < 160) {
      int s = tid / 10, o = tid - (tid / 10) * 10;
      float sum = bout[o];
#pragma unroll
      for (int kc = 0; kc < 4; ++kc)
#pragma unroll
        for (int sb = 0; sb < 4; ++sb) {
          short8 hv = H1f[kc * 64 + sb * 16 + s];
          int dbase = kc * 32 + sb * 8;
          float4_t w0 = *(const float4_t*)(wout + o * 128 + dbase);
          float4_t w1 = *(const float4_t*)(wout + o * 128 + dbase + 4);
#pragma unroll
          for (int j = 0; j < 4; ++j) {
            sum += bf2f((unsigned short)hv[j])     * w0[j];
            sum += bf2f((unsigned short)hv[j + 4]) * w1[j];
          }
        }
      out[(size_t)(n0 + s) * 10 + o] = sum;
    }
    __syncthreads();   // epilogue reads done before next half re-zeroes
  }
}

extern "C" void kernel_launch(void* const* d_in, const int* in_sizes, int n_in,
                              void* d_out, int out_size, void* d_ws, size_t ws_size,
                              hipStream_t stream) {
  const float* x    = (const float*)d_in[0];
  const float* wih0 = (const float*)d_in[1];
  const float* whh0 = (const float*)d_in[2];
  const float* bih0 = (const float*)d_in[3];
  const float* bhh0 = (const float*)d_in[4];
  const float* wih1 = (const float*)d_in[5];
  const float* whh1 = (const float*)d_in[6];
  const float* bih1 = (const float*)d_in[7];
  const float* bhh1 = (const float*)d_in[8];
  const float* wout = (const float*)d_in[9];
  const float* bout = (const float*)d_in[10];

  unsigned short* wp = (unsigned short*)d_ws;   // 425984 B used

  pack_weights<<<832, 256, 0, stream>>>(wih0, whh0, wih1, whh1, bih0, bhh0, wp);
  lstm_fused<<<256, 256, 0, stream>>>(x, wp, bih1, bhh1, wout, bout, (float*)d_out);
}